// Round 6
// baseline (149.627 us; speedup 1.0000x reference)
//
#include <hip/hip_runtime.h>
#include <math.h>

// B=4096, S=128, F=8, H1=64, H2=32
// Stage A: x1p = split_pack(relu(concat(x,time) @ Wc^T + bc)) via split-bf16 MFMA
// Stage B: fused LSTM1 || LSTM2(lag-1), 1024 thr (16 waves, 4/SIMD), MFMA split-state

typedef __bf16 bf16x8 __attribute__((ext_vector_type(8)));
typedef float f32x4 __attribute__((ext_vector_type(4)));

union F8 { uint4 q; unsigned u[4]; bf16x8 v; };

// fast activations: v_exp_f32 + v_rcp_f32 (saturate cleanly at extremes)
__device__ __forceinline__ float sigm(float x) {
  return __builtin_amdgcn_rcpf(1.f + __builtin_amdgcn_exp2f(x * -1.44269504f));
}
__device__ __forceinline__ float tanh_fast(float x) {
  return 1.f - 2.f * __builtin_amdgcn_rcpf(1.f + __builtin_amdgcn_exp2f(x * 2.88539008f));
}

// split f32 into bf16 hi (trunc) + bf16 lo (trunc residual), packed lo<<16|hi
__device__ __forceinline__ unsigned split_pack(float x) {
  unsigned u = __float_as_uint(x);
  float hif = __uint_as_float(u & 0xffff0000u);
  float lo = x - hif;
  return (u >> 16) | (__float_as_uint(lo) & 0xffff0000u);
}

// bf16 RNE of w, duplicated into both halves of a u32 (pairs with hi/lo slots)
__device__ __forceinline__ unsigned dup_bf(float w) {
  unsigned u = __float_as_uint(w);
  unsigned b = (u + 0x7fffu + ((u >> 16) & 1u)) >> 16;
  return b | (b << 16);
}

// ---------------- Kernel A: combine GEMM via split-bf16 MFMA ----------------
#define CB_PAD 40  // shorts per staged row (32 + 8): 80B, 16B-aligned rows

__global__ __launch_bounds__(256, 2) void combine_mfma(
    const float* __restrict__ x, const float* __restrict__ tme,
    const float* __restrict__ Wc, const float* __restrict__ bc,
    unsigned* __restrict__ x1p)
{
  __shared__ __align__(16) char smem[128 * 68 * 4];  // 34816 B, overlaid
  unsigned short (*sAh)[CB_PAD] = (unsigned short (*)[CB_PAD])(smem);
  unsigned short (*sAl)[CB_PAD] = (unsigned short (*)[CB_PAD])(smem + 10240);
  unsigned short (*sBh)[CB_PAD] = (unsigned short (*)[CB_PAD])(smem + 20480);
  unsigned short (*sBl)[CB_PAD] = (unsigned short (*)[CB_PAD])(smem + 25600);
  unsigned (*Cst)[68] = (unsigned (*)[68])smem;      // epilogue reuse
  __shared__ float sT[128];
  __shared__ float sWl[64];
  __shared__ float sBc[64];

  const int tid = threadIdx.x;
  const int lane = tid & 63;
  const int w = tid >> 6;
  const int r = lane & 15, grp = lane >> 4;
  const int M0 = blockIdx.y * 128, N0 = blockIdx.x * 64;

  if (tid < 128) sT[tid] = tme[M0 + tid];
  else if (tid < 192) sWl[tid - 128] = Wc[(size_t)(N0 + tid - 128) * 1025 + 1024];
  else sBc[tid - 192] = bc[N0 + tid - 192];

  f32x4 acc[2][4];
#pragma unroll
  for (int i = 0; i < 2; ++i)
#pragma unroll
    for (int j = 0; j < 4; ++j) acc[i][j] = f32x4{0.f, 0.f, 0.f, 0.f};

  for (int kt = 0; kt < 1024; kt += 32) {
#pragma unroll
    for (int i = 0; i < 4; ++i) {
      int idx = tid + i * 256;
      int row = idx >> 3, kq = idx & 7;
      float4 v = *(const float4*)&x[(size_t)(M0 + row) * 1024 + kt + kq * 4];
      unsigned u0 = __float_as_uint(v.x), u1 = __float_as_uint(v.y);
      unsigned u2 = __float_as_uint(v.z), u3 = __float_as_uint(v.w);
      uint2 hw = {(u0 >> 16) | (u1 & 0xffff0000u), (u2 >> 16) | (u3 & 0xffff0000u)};
      float l0 = v.x - __uint_as_float(u0 & 0xffff0000u);
      float l1 = v.y - __uint_as_float(u1 & 0xffff0000u);
      float l2 = v.z - __uint_as_float(u2 & 0xffff0000u);
      float l3 = v.w - __uint_as_float(u3 & 0xffff0000u);
      uint2 lw = {(__float_as_uint(l0) >> 16) | (__float_as_uint(l1) & 0xffff0000u),
                  (__float_as_uint(l2) >> 16) | (__float_as_uint(l3) & 0xffff0000u)};
      *(uint2*)&sAh[row][kq * 4] = hw;
      *(uint2*)&sAl[row][kq * 4] = lw;
    }
#pragma unroll
    for (int i = 0; i < 2; ++i) {
      int idx = tid + i * 256;
      int row = idx >> 3, kq = idx & 7;
      float4 v = *(const float4*)&Wc[(size_t)(N0 + row) * 1025 + kt + kq * 4];
      unsigned u0 = __float_as_uint(v.x), u1 = __float_as_uint(v.y);
      unsigned u2 = __float_as_uint(v.z), u3 = __float_as_uint(v.w);
      uint2 hw = {(u0 >> 16) | (u1 & 0xffff0000u), (u2 >> 16) | (u3 & 0xffff0000u)};
      float l0 = v.x - __uint_as_float(u0 & 0xffff0000u);
      float l1 = v.y - __uint_as_float(u1 & 0xffff0000u);
      float l2 = v.z - __uint_as_float(u2 & 0xffff0000u);
      float l3 = v.w - __uint_as_float(u3 & 0xffff0000u);
      uint2 lw = {(__float_as_uint(l0) >> 16) | (__float_as_uint(l1) & 0xffff0000u),
                  (__float_as_uint(l2) >> 16) | (__float_as_uint(l3) & 0xffff0000u)};
      *(uint2*)&sBh[row][kq * 4] = hw;
      *(uint2*)&sBl[row][kq * 4] = lw;
    }
    __syncthreads();

    F8 ah[2], al[2], bh[4], bl[4];
#pragma unroll
    for (int i = 0; i < 2; ++i) {
      ah[i].q = *(const uint4*)&sAh[w * 32 + i * 16 + r][grp * 8];
      al[i].q = *(const uint4*)&sAl[w * 32 + i * 16 + r][grp * 8];
    }
#pragma unroll
    for (int j = 0; j < 4; ++j) {
      bh[j].q = *(const uint4*)&sBh[j * 16 + r][grp * 8];
      bl[j].q = *(const uint4*)&sBl[j * 16 + r][grp * 8];
    }
#pragma unroll
    for (int i = 0; i < 2; ++i)
#pragma unroll
      for (int j = 0; j < 4; ++j) {
        acc[i][j] = __builtin_amdgcn_mfma_f32_16x16x32_bf16(ah[i].v, bh[j].v, acc[i][j], 0, 0, 0);
        acc[i][j] = __builtin_amdgcn_mfma_f32_16x16x32_bf16(ah[i].v, bl[j].v, acc[i][j], 0, 0, 0);
        acc[i][j] = __builtin_amdgcn_mfma_f32_16x16x32_bf16(al[i].v, bh[j].v, acc[i][j], 0, 0, 0);
      }
    __syncthreads();
  }

#pragma unroll
  for (int i = 0; i < 2; ++i) {
#pragma unroll
    for (int j = 0; j < 4; ++j) {
      int n = j * 16 + r;
      float wl = sWl[n], bv = sBc[n];
#pragma unroll
      for (int q = 0; q < 4; ++q) {
        int mm = w * 32 + i * 16 + 4 * grp + q;
        float v = acc[i][j][q] + sT[mm] * wl + bv;
        Cst[mm][n] = split_pack(fmaxf(v, 0.f));
      }
    }
  }
  __syncthreads();
#pragma unroll
  for (int i = 0; i < 8; ++i) {
    int idx = tid + i * 256;
    int row = idx >> 4, c4 = idx & 15;
    uint4 v = *(const uint4*)&Cst[row][c4 * 4];
    *(uint4*)&x1p[(size_t)(M0 + row) * 1024 + N0 + c4 * 4] = v;
  }
}

// ---------------- Kernel B: fused LSTM, 16 waves (4/SIMD), lag-1 L2 ---------
// wave w (0..15): L1 tile (vw = w>>2, j = w&3): h1 = vw*16 + 4*grp + j.
// L2 waves: w in {0..3, 8..11} (2 per SIMD under w%4 mapping): u = (w&3)+((w>>3)<<2),
//           h2 = 4*u + grp.
#define ROW1 136  // shorts per sh1 row: 128 h1-slots + 8 pad
#define ROW2 72   // shorts per sh2 row: 64 h2-slots + 8 pad

__global__ __launch_bounds__(1024, 4) void lstm_fused_mfma(
    const unsigned* __restrict__ x1p,
    const float* __restrict__ Wih1, const float* __restrict__ Whh1,
    const float* __restrict__ Wih2, const float* __restrict__ Whh2,
    const float* __restrict__ bih2, const float* __restrict__ bhh2,
    const float* __restrict__ Wout, const float* __restrict__ bout,
    float* __restrict__ out)
{
  extern __shared__ __align__(16) char smraw[];
  unsigned* sxw = (unsigned*)smraw;                                  // [128][16][8] u32, 64KB
  float* sWoT = (float*)(smraw + 65536);                             // [32][128], 16KB
  unsigned short (*sh1)[16][ROW1] =
      (unsigned short (*)[16][ROW1])(smraw + 65536 + 16384);         // [2][16][136]
  unsigned short (*sh2)[16][ROW2] =
      (unsigned short (*)[16][ROW2])(smraw + 65536 + 16384 + 8704);  // [2][16][72]
  float (*sOut)[16] = (float (*)[16])(smraw + 65536 + 16384 + 8704 + 4608);  // [8][16]

  const int tid = threadIdx.x;
  const int lane = tid & 63;
  const int w = tid >> 6;       // wave 0..15
  const int vw = w >> 2;        // L1 h-range 0..3
  const int j1 = w & 3;         // L1 sub-tile 0..3
  const bool isL2 = ((w >> 2) & 1) == 0;        // waves 0-3, 8-11
  const int u = (w & 3) + ((w >> 3) << 2);      // L2 tile 0..7
  const int col = lane & 15;    // A-row at pack time / batch col at run time
  const int grp = lane >> 4;    // k-slot group; C rows 4*grp+r
  const int b0 = blockIdx.x * 16;

  // ---- pack A-side weight fragments (once) ----
  const int m1 = col >> 2, g1 = col & 3;  // A row = 4*m + gate
  bf16x8 A1[5];  // L1 tile: chunks 0-3 = h1 (k=64), chunk 4 = x (8 dims)
  {
    const int wr = g1 * 64 + vw * 16 + 4 * m1 + j1;
#pragma unroll
    for (int c = 0; c < 5; ++c) {
      F8 f;
#pragma unroll
      for (int q = 0; q < 4; ++q) {
        float wv;
        if (c < 4) wv = Whh1[wr * 64 + c * 16 + grp * 4 + q];
        else { int d = grp * 4 + q; wv = (d < 8) ? Wih1[wr * 8 + d] : 0.f; }
        f.u[q] = dup_bf(wv);
      }
      A1[c] = f.v;
    }
  }
  bf16x8 A2[6];  // L2 tile: chunks 0-3 = h1, 4-5 = h2
  float bias2[4] = {0.f, 0.f, 0.f, 0.f};
  const int h2o = 4 * u + grp;
  if (isL2) {
    const int wr = g1 * 32 + 4 * u + m1;
#pragma unroll
    for (int c = 0; c < 6; ++c) {
      F8 f;
#pragma unroll
      for (int q = 0; q < 4; ++q) {
        float wv = (c < 4) ? Wih2[wr * 64 + c * 16 + grp * 4 + q]
                           : Whh2[wr * 32 + (c - 4) * 16 + grp * 4 + q];
        f.u[q] = dup_bf(wv);
      }
      A2[c] = f.v;
    }
#pragma unroll
    for (int r = 0; r < 4; ++r)
      bias2[r] = bih2[r * 32 + h2o] + bhh2[r * 32 + h2o];
  }

  // ---- LDS init ----
  for (int idx = tid; idx < 4096; idx += 1024) {  // Wout transpose -> [h2][t]
    int t = idx >> 5, h = idx & 31;
    sWoT[h * 128 + t] = Wout[idx];
  }
  {
    unsigned short* z = &sh1[0][0][0];
    for (int i2 = tid; i2 < 2 * 16 * ROW1; i2 += 1024) z[i2] = 0;
    unsigned short* z2 = &sh2[0][0][0];
    for (int i2 = tid; i2 < 2 * 16 * ROW2; i2 += 1024) z2[i2] = 0;
  }
  for (int idx = tid; idx < 16 * 128 * 8; idx += 1024) {
    int bb = idx >> 10, rem = idx & 1023;
    int t = rem >> 3, d = rem & 7;
    sxw[t * 128 + bb * 8 + d] = x1p[(size_t)(b0 + bb) * 1024 + rem];
  }
  __syncthreads();

  float c1 = 0.f;
  float c2 = 0.f;
  float accO = 0.f;
  int cur = 0;

  for (int t = 0; t <= 128; ++t) {  // phase t: L1(t) for t<128, L2(t-1) for t>0
    const bool doL1 = (t < 128);
    const bool doL2 = (t > 0) && isL2;

    F8 s1f[5], s2f[2];
#pragma unroll
    for (int c = 0; c < 4; ++c)
      s1f[c].q = *(const uint4*)&sh1[cur][col][c * 32 + grp * 8];
    if (isL2) {
#pragma unroll
      for (int c = 0; c < 2; ++c)
        s2f[c].q = *(const uint4*)&sh2[cur][col][c * 32 + grp * 8];
    }
    if (doL1)
      s1f[4].q = *(const uint4*)&sxw[t * 128 + col * 8 + (grp & 1) * 4];

    if (doL1) {
      f32x4 a = {0.f, 0.f, 0.f, 0.f};
#pragma unroll
      for (int c = 0; c < 5; ++c)
        a = __builtin_amdgcn_mfma_f32_16x16x32_bf16(A1[c], s1f[c].v, a, 0, 0, 0);
      // cell (b=col, h1 = vw*16 + 4*grp + j1)
      float ig = sigm(a[0]);
      float fg = sigm(a[1]);
      float tg = tanh_fast(a[2]);
      float og = sigm(a[3]);
      float cc = fg * c1 + ig * tg;
      c1 = cc;
      *(unsigned*)&sh1[cur ^ 1][col][2 * (vw * 16 + 4 * grp + j1)] =
          split_pack(og * tanh_fast(cc));
    }

    if (doL2) {
      f32x4 a = {bias2[0], bias2[1], bias2[2], bias2[3]};
#pragma unroll
      for (int c = 0; c < 4; ++c)
        a = __builtin_amdgcn_mfma_f32_16x16x32_bf16(A2[c], s1f[c].v, a, 0, 0, 0);
#pragma unroll
      for (int c = 0; c < 2; ++c)
        a = __builtin_amdgcn_mfma_f32_16x16x32_bf16(A2[4 + c], s2f[c].v, a, 0, 0, 0);
      float ig = sigm(a[0]);
      float fg = sigm(a[1]);
      float tg = tanh_fast(a[2]);
      float og = sigm(a[3]);
      float cc = fg * c2 + ig * tg;
      c2 = cc;
      float hn = og * tanh_fast(cc);
      accO += hn * sWoT[h2o * 128 + (t - 1)];
      *(unsigned*)&sh2[cur ^ 1][col][2 * h2o] = split_pack(hn);
    }

    __syncthreads();
    cur ^= 1;
  }

  // ---- output reduce: over grp (16/32 shuffles) then the 8 L2 waves ----
  if (isL2) {
    accO += __shfl_xor(accO, 16);
    accO += __shfl_xor(accO, 32);
    if (grp == 0) sOut[u][col] = accO;
  }
  __syncthreads();
  if (tid < 16) {
    float s = bout[0];
#pragma unroll
    for (int q = 0; q < 8; ++q) s += sOut[q][tid];
    out[b0 + tid] = s;
  }
}

extern "C" void kernel_launch(void* const* d_in, const int* in_sizes, int n_in,
                              void* d_out, int out_size, void* d_ws, size_t ws_size,
                              hipStream_t stream) {
  const float* x    = (const float*)d_in[0];
  const float* tme  = (const float*)d_in[1];
  const float* Wc   = (const float*)d_in[2];
  const float* bc   = (const float*)d_in[3];
  const float* Wih1 = (const float*)d_in[4];
  const float* Whh1 = (const float*)d_in[5];
  const float* Wih2 = (const float*)d_in[6];
  const float* Whh2 = (const float*)d_in[7];
  const float* bih2 = (const float*)d_in[8];
  const float* bhh2 = (const float*)d_in[9];
  const float* Wout = (const float*)d_in[10];
  const float* bout = (const float*)d_in[11];
  float* outp = (float*)d_out;
  unsigned* x1p = (unsigned*)d_ws;  // [4096][1024] packed split-bf16 = 16.78 MB

  dim3 gA(16, 32);  // N/64, M/128
  combine_mfma<<<gA, 256, 0, stream>>>(x, tme, Wc, bc, x1p);

  const size_t smem = 65536 + 16384 + 8704 + 4608 + 8 * 16 * sizeof(float);
  hipFuncSetAttribute(reinterpret_cast<const void*>(lstm_fused_mfma),
                      hipFuncAttributeMaxDynamicSharedMemorySize, (int)smem);
  lstm_fused_mfma<<<256, 1024, smem, stream>>>(x1p, Wih1, Whh1, Wih2, Whh2,
                                               bih2, bhh2, Wout, bout, outp);
}

// Round 7
// 125.307 us; speedup vs baseline: 1.1941x; 1.1941x over previous
//
#include <hip/hip_runtime.h>
#include <math.h>

// B=4096, S=128, F=8, H1=64, H2=32
// Stage A: x1h = fp16(relu(concat(x,time) @ Wc^T + bc)) via split-bf16 MFMA
// Stage B: fused LSTM1 || LSTM2(lag-1), 8 waves (2/SIMD), fp16 MFMA state+weights

typedef __bf16 bf16x8 __attribute__((ext_vector_type(8)));
typedef _Float16 f16x8 __attribute__((ext_vector_type(8)));
typedef float f32x4 __attribute__((ext_vector_type(4)));

union F8 { uint4 q; unsigned u[4]; bf16x8 v; };
union H8 { uint4 q; _Float16 h[8]; f16x8 v; };
union H2 { unsigned u; _Float16 h[2]; };

// fast activations: v_exp_f32 + v_rcp_f32 (saturate cleanly at extremes)
__device__ __forceinline__ float sigm(float x) {
  return __builtin_amdgcn_rcpf(1.f + __builtin_amdgcn_exp2f(x * -1.44269504f));
}
__device__ __forceinline__ float tanh_fast(float x) {
  return 1.f - 2.f * __builtin_amdgcn_rcpf(1.f + __builtin_amdgcn_exp2f(x * 2.88539008f));
}

// ---------------- Kernel A: combine GEMM via split-bf16 MFMA ----------------
// M=4096(batch) x N=1024 x K=1024 (+time col, bias, relu), fp16 output.
#define CB_PAD 40  // shorts per staged row (32 + 8)

__global__ __launch_bounds__(256, 2) void combine_mfma(
    const float* __restrict__ x, const float* __restrict__ tme,
    const float* __restrict__ Wc, const float* __restrict__ bc,
    unsigned* __restrict__ x1u)   // fp16 pairs: [4096][512] u32
{
  __shared__ __align__(16) char smem[128 * 68 * 4];  // 34816 B, overlaid
  unsigned short (*sAh)[CB_PAD] = (unsigned short (*)[CB_PAD])(smem);
  unsigned short (*sAl)[CB_PAD] = (unsigned short (*)[CB_PAD])(smem + 10240);
  unsigned short (*sBh)[CB_PAD] = (unsigned short (*)[CB_PAD])(smem + 20480);
  unsigned short (*sBl)[CB_PAD] = (unsigned short (*)[CB_PAD])(smem + 25600);
  _Float16 (*Cst)[72] = (_Float16 (*)[72])smem;      // epilogue reuse, 18432 B
  __shared__ float sT[128];
  __shared__ float sWl[64];
  __shared__ float sBc[64];

  const int tid = threadIdx.x;
  const int lane = tid & 63;
  const int w = tid >> 6;
  const int r = lane & 15, grp = lane >> 4;
  const int M0 = blockIdx.y * 128, N0 = blockIdx.x * 64;

  if (tid < 128) sT[tid] = tme[M0 + tid];
  else if (tid < 192) sWl[tid - 128] = Wc[(size_t)(N0 + tid - 128) * 1025 + 1024];
  else sBc[tid - 192] = bc[N0 + tid - 192];

  f32x4 acc[2][4];
#pragma unroll
  for (int i = 0; i < 2; ++i)
#pragma unroll
    for (int j = 0; j < 4; ++j) acc[i][j] = f32x4{0.f, 0.f, 0.f, 0.f};

  for (int kt = 0; kt < 1024; kt += 32) {
#pragma unroll
    for (int i = 0; i < 4; ++i) {
      int idx = tid + i * 256;
      int row = idx >> 3, kq = idx & 7;
      float4 v = *(const float4*)&x[(size_t)(M0 + row) * 1024 + kt + kq * 4];
      unsigned u0 = __float_as_uint(v.x), u1 = __float_as_uint(v.y);
      unsigned u2 = __float_as_uint(v.z), u3 = __float_as_uint(v.w);
      uint2 hw = {(u0 >> 16) | (u1 & 0xffff0000u), (u2 >> 16) | (u3 & 0xffff0000u)};
      float l0 = v.x - __uint_as_float(u0 & 0xffff0000u);
      float l1 = v.y - __uint_as_float(u1 & 0xffff0000u);
      float l2 = v.z - __uint_as_float(u2 & 0xffff0000u);
      float l3 = v.w - __uint_as_float(u3 & 0xffff0000u);
      uint2 lw = {(__float_as_uint(l0) >> 16) | (__float_as_uint(l1) & 0xffff0000u),
                  (__float_as_uint(l2) >> 16) | (__float_as_uint(l3) & 0xffff0000u)};
      *(uint2*)&sAh[row][kq * 4] = hw;
      *(uint2*)&sAl[row][kq * 4] = lw;
    }
#pragma unroll
    for (int i = 0; i < 2; ++i) {
      int idx = tid + i * 256;
      int row = idx >> 3, kq = idx & 7;
      float4 v = *(const float4*)&Wc[(size_t)(N0 + row) * 1025 + kt + kq * 4];
      unsigned u0 = __float_as_uint(v.x), u1 = __float_as_uint(v.y);
      unsigned u2 = __float_as_uint(v.z), u3 = __float_as_uint(v.w);
      uint2 hw = {(u0 >> 16) | (u1 & 0xffff0000u), (u2 >> 16) | (u3 & 0xffff0000u)};
      float l0 = v.x - __uint_as_float(u0 & 0xffff0000u);
      float l1 = v.y - __uint_as_float(u1 & 0xffff0000u);
      float l2 = v.z - __uint_as_float(u2 & 0xffff0000u);
      float l3 = v.w - __uint_as_float(u3 & 0xffff0000u);
      uint2 lw = {(__float_as_uint(l0) >> 16) | (__float_as_uint(l1) & 0xffff0000u),
                  (__float_as_uint(l2) >> 16) | (__float_as_uint(l3) & 0xffff0000u)};
      *(uint2*)&sBh[row][kq * 4] = hw;
      *(uint2*)&sBl[row][kq * 4] = lw;
    }
    __syncthreads();

    F8 ah[2], al[2], bh[4], bl[4];
#pragma unroll
    for (int i = 0; i < 2; ++i) {
      ah[i].q = *(const uint4*)&sAh[w * 32 + i * 16 + r][grp * 8];
      al[i].q = *(const uint4*)&sAl[w * 32 + i * 16 + r][grp * 8];
    }
#pragma unroll
    for (int j = 0; j < 4; ++j) {
      bh[j].q = *(const uint4*)&sBh[j * 16 + r][grp * 8];
      bl[j].q = *(const uint4*)&sBl[j * 16 + r][grp * 8];
    }
#pragma unroll
    for (int i = 0; i < 2; ++i)
#pragma unroll
      for (int j = 0; j < 4; ++j) {
        acc[i][j] = __builtin_amdgcn_mfma_f32_16x16x32_bf16(ah[i].v, bh[j].v, acc[i][j], 0, 0, 0);
        acc[i][j] = __builtin_amdgcn_mfma_f32_16x16x32_bf16(ah[i].v, bl[j].v, acc[i][j], 0, 0, 0);
        acc[i][j] = __builtin_amdgcn_mfma_f32_16x16x32_bf16(al[i].v, bh[j].v, acc[i][j], 0, 0, 0);
      }
    __syncthreads();
  }

  // epilogue: time col + bias + relu -> fp16 -> LDS transpose -> coalesced store
#pragma unroll
  for (int i = 0; i < 2; ++i) {
#pragma unroll
    for (int j = 0; j < 4; ++j) {
      int n = j * 16 + r;
      float wl = sWl[n], bv = sBc[n];
#pragma unroll
      for (int q = 0; q < 4; ++q) {
        int mm = w * 32 + i * 16 + 4 * grp + q;
        float v = acc[i][j][q] + sT[mm] * wl + bv;
        Cst[mm][n] = (_Float16)fmaxf(v, 0.f);
      }
    }
  }
  __syncthreads();
#pragma unroll
  for (int i = 0; i < 4; ++i) {   // 128 rows x 8 uint4 = 1024 uint4
    int idx = tid + i * 256;
    int row = idx >> 3, c8 = idx & 7;
    uint4 v = *(const uint4*)&Cst[row][c8 * 8];
    *(uint4*)&x1u[(size_t)(M0 + row) * 512 + (N0 >> 1) + c8 * 4] = v;
  }
}

// ---------------- Kernel B: fused LSTM fp16, 8 waves, lag-1 L2 --------------
// wave w: vw = w>>1, wsub = w&1.
// L1: tiles jj=0,1 -> h1 = vw*16 + 4*grp + 2*wsub + jj.
// L2: tile u = 2*vw + wsub -> h2 = 4*u + grp.
#define ROW1 72   // shorts per sh1 row: 64 h1 slots + 8 pad (144B, 16B-aligned)
#define ROW2 40   // shorts per sh2 row: 32 h2 slots + 8 pad (80B)

__global__ __launch_bounds__(512, 2) void lstm_fused_mfma(
    const unsigned* __restrict__ x1u,
    const float* __restrict__ Wih1, const float* __restrict__ Whh1,
    const float* __restrict__ Wih2, const float* __restrict__ Whh2,
    const float* __restrict__ bih2, const float* __restrict__ bhh2,
    const float* __restrict__ Wout, const float* __restrict__ bout,
    float* __restrict__ out)
{
  __shared__ __align__(16) unsigned sxw[128 * 16 * 4];         // fp16 x [t][b][4u32] 32KB
  __shared__ float sWoT[32 * 128];                             // Wout^T [h2][t] 16KB
  __shared__ __align__(16) unsigned short sh1[2][16][ROW1];    // 4608B
  __shared__ __align__(16) unsigned short sh2[2][16][ROW2];    // 2560B
  __shared__ float sOut[8][16];
  __shared__ __align__(16) unsigned zbufu[4];                  // 16B zeros

  const int tid = threadIdx.x;
  const int lane = tid & 63;
  const int w = tid >> 6;       // wave 0..7
  const int vw = w >> 1;
  const int wsub = w & 1;
  const int col = lane & 15;    // A-row at pack time / batch col at run time
  const int grp = lane >> 4;    // k-slot group; C rows 4*grp+r
  const int b0 = blockIdx.x * 16;

  // ---- pack fp16 A-side weight fragments (once) ----
  // lane (col,grp) holds A[row=col][k = c*32 + grp*8 + q], q=0..7.
  const int m1 = col >> 2, g1 = col & 3;  // tile row = 4*m + gate
  f16x8 A1[2][3];  // L1 tiles jj: c0,c1 = Whh1 (k=64), c2 = Wih1 (8 of 32)
#pragma unroll
  for (int jj = 0; jj < 2; ++jj) {
    const int wr = g1 * 64 + vw * 16 + 4 * m1 + (2 * wsub + jj);
#pragma unroll
    for (int c = 0; c < 3; ++c) {
      H8 f;
#pragma unroll
      for (int q = 0; q < 8; ++q) {
        float wv = 0.f;
        if (c < 2) wv = Whh1[wr * 64 + c * 32 + grp * 8 + q];
        else if (grp == 0) wv = Wih1[wr * 8 + q];
        f.h[q] = (_Float16)wv;
      }
      A1[jj][c] = f.v;
    }
  }
  f16x8 A2[3];  // L2: c0,c1 = Wih2 (k=64), c2 = Whh2 (k=32)
  const int u = 2 * vw + wsub;
  {
    const int wr = g1 * 32 + 4 * u + m1;
#pragma unroll
    for (int c = 0; c < 3; ++c) {
      H8 f;
#pragma unroll
      for (int q = 0; q < 8; ++q) {
        float wv = (c < 2) ? Wih2[wr * 64 + c * 32 + grp * 8 + q]
                           : Whh2[wr * 32 + grp * 8 + q];
        f.h[q] = (_Float16)wv;
      }
      A2[c] = f.v;
    }
  }
  const int h2o = 4 * u + grp;
  float bias2[4];
#pragma unroll
  for (int r = 0; r < 4; ++r)
    bias2[r] = bih2[r * 32 + h2o] + bhh2[r * 32 + h2o];

  // ---- LDS init ----
  for (int idx = tid; idx < 4096; idx += 512) {  // Wout -> [h2][t]
    int t = idx >> 5, h = idx & 31;
    sWoT[h * 128 + t] = Wout[idx];
  }
  {
    unsigned short* z = &sh1[0][0][0];
    for (int i2 = tid; i2 < 2 * 16 * ROW1; i2 += 512) z[i2] = 0;
    unsigned short* z2 = &sh2[0][0][0];
    for (int i2 = tid; i2 < 2 * 16 * ROW2; i2 += 512) z2[i2] = 0;
    if (tid < 4) zbufu[tid] = 0;
  }
  for (int idx = tid; idx < 16 * 512; idx += 512) {  // x preload: [t][b][4u32]
    int bb = idx >> 9, rem = idx & 511;
    int t = rem >> 2, pr = rem & 3;
    sxw[t * 64 + bb * 4 + pr] = x1u[(size_t)(b0 + bb) * 512 + rem];
  }
  __syncthreads();

  float c1[2] = {0.f, 0.f};
  float c2 = 0.f;
  float accO = 0.f;

#define PHASE(T, CUR, DO_L1, DO_L2)                                            \
  {                                                                            \
    H8 s0, s1, s2, sx;                                                         \
    s0.q = *(const uint4*)&sh1[CUR][col][grp * 8];                             \
    s1.q = *(const uint4*)&sh1[CUR][col][32 + grp * 8];                        \
    s2.q = *(const uint4*)&sh2[CUR][col][grp * 8];                             \
    if (DO_L1) {                                                               \
      const unsigned* xa = (grp == 0) ? &sxw[(T) * 64 + col * 4] : zbufu;      \
      sx.q = *(const uint4*)xa;                                                \
      f32x4 a0 = {0.f, 0.f, 0.f, 0.f}, a1 = {0.f, 0.f, 0.f, 0.f};              \
      a0 = __builtin_amdgcn_mfma_f32_16x16x32_f16(A1[0][0], s0.v, a0, 0, 0, 0);\
      a1 = __builtin_amdgcn_mfma_f32_16x16x32_f16(A1[1][0], s0.v, a1, 0, 0, 0);\
      a0 = __builtin_amdgcn_mfma_f32_16x16x32_f16(A1[0][1], s1.v, a0, 0, 0, 0);\
      a1 = __builtin_amdgcn_mfma_f32_16x16x32_f16(A1[1][1], s1.v, a1, 0, 0, 0);\
      a0 = __builtin_amdgcn_mfma_f32_16x16x32_f16(A1[0][2], sx.v, a0, 0, 0, 0);\
      a1 = __builtin_amdgcn_mfma_f32_16x16x32_f16(A1[1][2], sx.v, a1, 0, 0, 0);\
      float ig0 = sigm(a0[0]), fg0 = sigm(a0[1]);                              \
      float tg0 = tanh_fast(a0[2]), og0 = sigm(a0[3]);                         \
      float cc0 = fg0 * c1[0] + ig0 * tg0;                                     \
      c1[0] = cc0;                                                             \
      float ig1 = sigm(a1[0]), fg1 = sigm(a1[1]);                              \
      float tg1 = tanh_fast(a1[2]), og1 = sigm(a1[3]);                         \
      float cc1 = fg1 * c1[1] + ig1 * tg1;                                     \
      c1[1] = cc1;                                                             \
      H2 p;                                                                    \
      p.h[0] = (_Float16)(og0 * tanh_fast(cc0));                               \
      p.h[1] = (_Float16)(og1 * tanh_fast(cc1));                               \
      *(unsigned*)&sh1[(CUR) ^ 1][col][vw * 16 + 4 * grp + 2 * wsub] = p.u;    \
    }                                                                          \
    if (DO_L2) {                                                               \
      f32x4 a = {bias2[0], bias2[1], bias2[2], bias2[3]};                      \
      a = __builtin_amdgcn_mfma_f32_16x16x32_f16(A2[0], s0.v, a, 0, 0, 0);     \
      a = __builtin_amdgcn_mfma_f32_16x16x32_f16(A2[1], s1.v, a, 0, 0, 0);     \
      a = __builtin_amdgcn_mfma_f32_16x16x32_f16(A2[2], s2.v, a, 0, 0, 0);     \
      float ig = sigm(a[0]), fg = sigm(a[1]);                                  \
      float tg = tanh_fast(a[2]), og = sigm(a[3]);                             \
      float cc = fg * c2 + ig * tg;                                            \
      c2 = cc;                                                                 \
      float hn = og * tanh_fast(cc);                                           \
      accO += hn * sWoT[h2o * 128 + (T) - 1];                                  \
      *(_Float16*)&sh2[(CUR) ^ 1][col][h2o] = (_Float16)hn;                    \
    }                                                                          \
    __syncthreads();                                                           \
  }

  PHASE(0, 0, true, false);
  PHASE(1, 1, true, true);
  for (int tt = 1; tt < 64; ++tt) {
    const int t0 = 2 * tt;
    PHASE(t0, 0, true, true);
    PHASE(t0 + 1, 1, true, true);
  }
  PHASE(128, 0, false, true);
#undef PHASE

  // ---- output reduce: over grp (16/32 shuffles) then 8 waves ----
  accO += __shfl_xor(accO, 16);
  accO += __shfl_xor(accO, 32);
  if (grp == 0) sOut[u][col] = accO;
  __syncthreads();
  if (tid < 16) {
    float s = bout[0];
#pragma unroll
    for (int q = 0; q < 8; ++q) s += sOut[q][tid];
    out[b0 + tid] = s;
  }
}

extern "C" void kernel_launch(void* const* d_in, const int* in_sizes, int n_in,
                              void* d_out, int out_size, void* d_ws, size_t ws_size,
                              hipStream_t stream) {
  const float* x    = (const float*)d_in[0];
  const float* tme  = (const float*)d_in[1];
  const float* Wc   = (const float*)d_in[2];
  const float* bc   = (const float*)d_in[3];
  const float* Wih1 = (const float*)d_in[4];
  const float* Whh1 = (const float*)d_in[5];
  const float* Wih2 = (const float*)d_in[6];
  const float* Whh2 = (const float*)d_in[7];
  const float* bih2 = (const float*)d_in[8];
  const float* bhh2 = (const float*)d_in[9];
  const float* Wout = (const float*)d_in[10];
  const float* bout = (const float*)d_in[11];
  float* outp = (float*)d_out;
  unsigned* x1u = (unsigned*)d_ws;  // [4096][512] fp16-pair u32 = 8.39 MB

  dim3 gA(16, 32);  // N/64, M/128
  combine_mfma<<<gA, 256, 0, stream>>>(x, tme, Wc, bc, x1u);
  lstm_fused_mfma<<<256, 512, 0, stream>>>(x1u, Wih1, Whh1, Wih2, Whh2,
                                           bih2, bhh2, Wout, bout, outp);
}

// Round 8
// 116.417 us; speedup vs baseline: 1.2853x; 1.0764x over previous
//
#include <hip/hip_runtime.h>
#include <math.h>

// B=4096, S=128, F=8, H1=64, H2=32
// Stage A: x1u = fp16(relu(concat(x,time) @ Wc^T + bc)), pure fp16 MFMA GEMM
// Stage B: fused LSTM1 || LSTM2(lag-1), 12 waves (3/SIMD), fp16 MFMA

typedef _Float16 f16x8 __attribute__((ext_vector_type(8)));
typedef float f32x4 __attribute__((ext_vector_type(4)));

union H8 { uint4 q; _Float16 h[8]; f16x8 v; };
union H2u { unsigned u; _Float16 h[2]; };

#define MF(A, B, C) __builtin_amdgcn_mfma_f32_16x16x32_f16(A, B, C, 0, 0, 0)

__device__ __forceinline__ float sigm(float x) {
  return __builtin_amdgcn_rcpf(1.f + __builtin_amdgcn_exp2f(x * -1.44269504f));
}
__device__ __forceinline__ float tanh_fast(float x) {
  return 1.f - 2.f * __builtin_amdgcn_rcpf(1.f + __builtin_amdgcn_exp2f(x * 2.88539008f));
}

// ---------------- Kernel A: combine GEMM, fp16 MFMA -------------------------
// M=4096 x N=1024 x K=1024 (+time col + bias + relu), fp16 out. BM=128 BN=64 BK=64.
#define CROW 72  // fp16 slots per staged row (64 + 8 pad) = 144 B

__global__ __launch_bounds__(256, 2) void combine_mfma(
    const float* __restrict__ x, const float* __restrict__ tme,
    const float* __restrict__ Wc, const float* __restrict__ bc,
    unsigned* __restrict__ x1u)   // fp16 pairs: [4096][512] u32
{
  __shared__ __align__(16) _Float16 sA[128][CROW];  // 18432 B
  __shared__ __align__(16) _Float16 sB[64][CROW];   // 9216 B
  __shared__ float sT[128];
  __shared__ float sWl[64];
  __shared__ float sBc[64];
  _Float16 (*Cst)[CROW] = sA;  // epilogue overlay

  const int tid = threadIdx.x;
  const int lane = tid & 63;
  const int w = tid >> 6;
  const int r = lane & 15, grp = lane >> 4;
  const int M0 = blockIdx.y * 128, N0 = blockIdx.x * 64;

  if (tid < 128) sT[tid] = tme[M0 + tid];
  else if (tid < 192) sWl[tid - 128] = Wc[(size_t)(N0 + tid - 128) * 1025 + 1024];
  else sBc[tid - 192] = bc[N0 + tid - 192];

  f32x4 acc[2][4];
#pragma unroll
  for (int i = 0; i < 2; ++i)
#pragma unroll
    for (int j = 0; j < 4; ++j) acc[i][j] = f32x4{0.f, 0.f, 0.f, 0.f};

  for (int kt = 0; kt < 1024; kt += 64) {
    // stage A: 128 rows x 64 k = 2048 float4, 8/thread
#pragma unroll
    for (int i = 0; i < 8; ++i) {
      int idx = tid + i * 256;
      int row = idx >> 4, kq = idx & 15;
      float4 v = *(const float4*)&x[(size_t)(M0 + row) * 1024 + kt + kq * 4];
      H2u p0, p1;
      p0.h[0] = (_Float16)v.x; p0.h[1] = (_Float16)v.y;
      p1.h[0] = (_Float16)v.z; p1.h[1] = (_Float16)v.w;
      *(uint2*)&sA[row][kq * 4] = uint2{p0.u, p1.u};
    }
    // stage B: 64 rows x 64 k = 1024 float4, 4/thread
#pragma unroll
    for (int i = 0; i < 4; ++i) {
      int idx = tid + i * 256;
      int row = idx >> 4, kq = idx & 15;
      float4 v = *(const float4*)&Wc[(size_t)(N0 + row) * 1025 + kt + kq * 4];
      H2u p0, p1;
      p0.h[0] = (_Float16)v.x; p0.h[1] = (_Float16)v.y;
      p1.h[0] = (_Float16)v.z; p1.h[1] = (_Float16)v.w;
      *(uint2*)&sB[row][kq * 4] = uint2{p0.u, p1.u};
    }
    __syncthreads();

    H8 af[2][2], bf[4][2];
#pragma unroll
    for (int i = 0; i < 2; ++i)
#pragma unroll
      for (int c = 0; c < 2; ++c)
        af[i][c].q = *(const uint4*)&sA[w * 32 + i * 16 + r][c * 32 + grp * 8];
#pragma unroll
    for (int j = 0; j < 4; ++j)
#pragma unroll
      for (int c = 0; c < 2; ++c)
        bf[j][c].q = *(const uint4*)&sB[j * 16 + r][c * 32 + grp * 8];
#pragma unroll
    for (int i = 0; i < 2; ++i)
#pragma unroll
      for (int j = 0; j < 4; ++j) {
        acc[i][j] = MF(af[i][0].v, bf[j][0].v, acc[i][j]);
        acc[i][j] = MF(af[i][1].v, bf[j][1].v, acc[i][j]);
      }
    __syncthreads();
  }

  // epilogue: time col + bias + relu -> fp16 -> LDS transpose -> coalesced store
#pragma unroll
  for (int i = 0; i < 2; ++i) {
#pragma unroll
    for (int j = 0; j < 4; ++j) {
      int n = j * 16 + r;
      float wl = sWl[n], bv = sBc[n];
#pragma unroll
      for (int q = 0; q < 4; ++q) {
        int mm = w * 32 + i * 16 + 4 * grp + q;
        float v = acc[i][j][q] + sT[mm] * wl + bv;
        Cst[mm][n] = (_Float16)fmaxf(v, 0.f);
      }
    }
  }
  __syncthreads();
#pragma unroll
  for (int i = 0; i < 4; ++i) {   // 128 rows x 8 uint4 = 1024 uint4
    int idx = tid + i * 256;
    int row = idx >> 3, c8 = idx & 7;
    uint4 v = *(const uint4*)&Cst[row][c8 * 8];
    *(uint4*)&x1u[(size_t)(M0 + row) * 512 + (N0 >> 1) + c8 * 4] = v;
  }
}

// ---------------- Kernel B: fused LSTM fp16, 12 waves (3/SIMD) --------------
// Tiles: L1 tile p (0..15): h1 = 4p+grp; L2 tile q (0..7): h2 = 4q+grp.
// wave w<8: L1 tile w + L2 tile w; wave>=8: L1 tiles 8+2(w-8), 9+2(w-8).
#define ROW1 72   // shorts per sh1 row: 64 h1 slots + 8 pad
#define ROW2 40   // shorts per sh2 row: 32 h2 slots + 8 pad

__global__ __launch_bounds__(768, 3) void lstm_fused_mfma(
    const unsigned* __restrict__ x1u,
    const float* __restrict__ Wih1, const float* __restrict__ Whh1,
    const float* __restrict__ Wih2, const float* __restrict__ Whh2,
    const float* __restrict__ bih2, const float* __restrict__ bhh2,
    const float* __restrict__ Wout, const float* __restrict__ bout,
    float* __restrict__ out)
{
  __shared__ __align__(16) unsigned sxw[128 * 16 * 4];       // fp16 x [t][b][4u32] 32KB
  __shared__ float sWoT[32 * 132];                           // Wout^T [h2][t+pad] 16896B
  __shared__ __align__(16) unsigned short sh1[2][16][ROW1];  // 4608B
  __shared__ __align__(16) unsigned short sh2[2][16][ROW2];  // 2560B
  __shared__ float sOut[8][16];

  const int tid = threadIdx.x;
  const int lane = tid & 63;
  const int w = tid >> 6;       // wave 0..11
  const int col = lane & 15;    // A-row at pack time / batch col at run time
  const int grp = lane >> 4;    // k-slot group; C rows 4*grp+r (r = gate)
  const int b0 = blockIdx.x * 16;
  const bool loWave = (w < 8);
  const int p0 = loWave ? w : (8 + 2 * (w - 8));

  // ---- pack fp16 A-side weight fragments (once) ----
  const int m1 = col >> 2, g1 = col & 3;  // A row = 4*m + gate
  f16x8 A1[2][3];  // per L1 tile: c0,c1 = Whh1 (k=64), c2 = Wih1 (8 of 32)
#pragma unroll
  for (int jj = 0; jj < 2; ++jj) {
    const int p = loWave ? p0 : (p0 + jj);
    const int wr = g1 * 64 + 4 * p + m1;
#pragma unroll
    for (int c = 0; c < 3; ++c) {
      H8 f;
#pragma unroll
      for (int q = 0; q < 8; ++q) {
        float wv = 0.f;
        if (c < 2) wv = Whh1[wr * 64 + c * 32 + grp * 8 + q];
        else if (grp == 0) wv = Wih1[wr * 8 + q];
        f.h[q] = (_Float16)wv;
      }
      A1[jj][c] = f.v;
    }
  }
  f16x8 A2[3];  // L2: c0,c1 = Wih2 (k=64), c2 = Whh2 (k=32)
  float bias2[4] = {0.f, 0.f, 0.f, 0.f};
  const int h2o = 4 * (w & 7) + grp;
  if (loWave) {
    const int wr = g1 * 32 + 4 * w + m1;
#pragma unroll
    for (int c = 0; c < 3; ++c) {
      H8 f;
#pragma unroll
      for (int q = 0; q < 8; ++q) {
        float wv = (c < 2) ? Wih2[wr * 64 + c * 32 + grp * 8 + q]
                           : Whh2[wr * 32 + grp * 8 + q];
        f.h[q] = (_Float16)wv;
      }
      A2[c] = f.v;
    }
#pragma unroll
    for (int r = 0; r < 4; ++r)
      bias2[r] = bih2[r * 32 + h2o] + bhh2[r * 32 + h2o];
  }

  // ---- LDS init ----
  for (int idx = tid; idx < 4096; idx += 768) {  // Wout -> [h2][t], pad stride 132
    int t = idx >> 5, h = idx & 31;
    sWoT[h * 132 + t] = Wout[idx];
  }
  {
    unsigned short* z = &sh1[0][0][0];
    for (int i2 = tid; i2 < 2 * 16 * ROW1; i2 += 768) z[i2] = 0;
    unsigned short* z2 = &sh2[0][0][0];
    for (int i2 = tid; i2 < 2 * 16 * ROW2; i2 += 768) z2[i2] = 0;
  }
  for (int idx = tid; idx < 16 * 512; idx += 768) {  // x preload: [t][b][4u32]
    int bb = idx >> 9, rem = idx & 511;
    int t = rem >> 2, pr = rem & 3;
    sxw[t * 64 + bb * 4 + pr] = x1u[(size_t)(b0 + bb) * 512 + rem];
  }
  __syncthreads();

  float c1a = 0.f, c1b = 0.f, c2 = 0.f, accO = 0.f, wov = 0.f;
  H8 sxv;
  sxv.q = *(const uint4*)&sxw[col * 4];  // x(0)

#define PHASE(T, CUR, DO_L1, DO_L2)                                            \
  {                                                                            \
    H8 s0, s1;                                                                 \
    s0.q = *(const uint4*)&sh1[CUR][col][grp * 8];                             \
    s1.q = *(const uint4*)&sh1[CUR][col][32 + grp * 8];                        \
    H8 sxn;                                                                    \
    { const int tn = ((T) < 127) ? (T) + 1 : 127;                              \
      sxn.q = *(const uint4*)&sxw[tn * 64 + col * 4]; }                        \
    if (loWave) {                                                              \
      const float won = sWoT[h2o * 132 + (((T) < 127) ? (T) : 127)];           \
      if (DO_L2) {                                                             \
        H8 s2;                                                                 \
        s2.q = *(const uint4*)&sh2[CUR][col][grp * 8];                         \
        f32x4 a = {bias2[0], bias2[1], bias2[2], bias2[3]};                    \
        a = MF(A2[0], s0.v, a);                                                \
        a = MF(A2[1], s1.v, a);                                                \
        a = MF(A2[2], s2.v, a);                                                \
        float ig = sigm(a[0]), fg = sigm(a[1]);                                \
        float tg = tanh_fast(a[2]), og = sigm(a[3]);                           \
        float cc = fg * c2 + ig * tg;                                          \
        c2 = cc;                                                               \
        float hn = og * tanh_fast(cc);                                         \
        accO += hn * wov;                                                      \
        *(_Float16*)&sh2[(CUR) ^ 1][col][h2o] = (_Float16)hn;                  \
      }                                                                        \
      if (DO_L1) {                                                             \
        f32x4 a = {0.f, 0.f, 0.f, 0.f};                                        \
        a = MF(A1[0][0], s0.v, a);                                             \
        a = MF(A1[0][1], s1.v, a);                                             \
        a = MF(A1[0][2], sxv.v, a);                                            \
        float ig = sigm(a[0]), fg = sigm(a[1]);                                \
        float tg = tanh_fast(a[2]), og = sigm(a[3]);                           \
        float cc = fg * c1a + ig * tg;                                         \
        c1a = cc;                                                              \
        *(_Float16*)&sh1[(CUR) ^ 1][col][4 * p0 + grp] =                       \
            (_Float16)(og * tanh_fast(cc));                                    \
      }                                                                        \
      wov = won;                                                               \
    } else if (DO_L1) {                                                        \
      f32x4 aA = {0.f, 0.f, 0.f, 0.f}, aB = {0.f, 0.f, 0.f, 0.f};              \
      aA = MF(A1[0][0], s0.v, aA);                                             \
      aB = MF(A1[1][0], s0.v, aB);                                             \
      aA = MF(A1[0][1], s1.v, aA);                                             \
      aB = MF(A1[1][1], s1.v, aB);                                             \
      aA = MF(A1[0][2], sxv.v, aA);                                            \
      aB = MF(A1[1][2], sxv.v, aB);                                            \
      float ig0 = sigm(aA[0]), fg0 = sigm(aA[1]);                              \
      float tg0 = tanh_fast(aA[2]), og0 = sigm(aA[3]);                         \
      float cc0 = fg0 * c1a + ig0 * tg0;                                       \
      c1a = cc0;                                                               \
      *(_Float16*)&sh1[(CUR) ^ 1][col][4 * p0 + grp] =                         \
          (_Float16)(og0 * tanh_fast(cc0));                                    \
      float ig1 = sigm(aB[0]), fg1 = sigm(aB[1]);                              \
      float tg1 = tanh_fast(aB[2]), og1 = sigm(aB[3]);                         \
      float cc1 = fg1 * c1b + ig1 * tg1;                                       \
      c1b = cc1;                                                               \
      *(_Float16*)&sh1[(CUR) ^ 1][col][4 * (p0 + 1) + grp] =                   \
          (_Float16)(og1 * tanh_fast(cc1));                                    \
    }                                                                          \
    sxv = sxn;                                                                 \
    __syncthreads();                                                           \
  }

  PHASE(0, 0, true, false);
  PHASE(1, 1, true, true);
  for (int tt = 1; tt < 64; ++tt) {
    const int t0 = 2 * tt;
    PHASE(t0, 0, true, true);
    PHASE(t0 + 1, 1, true, true);
  }
  PHASE(128, 0, false, true);
#undef PHASE

  // ---- output reduce: over grp (16/32 shuffles) then the 8 L2 waves ----
  if (loWave) {
    accO += __shfl_xor(accO, 16);
    accO += __shfl_xor(accO, 32);
    if (grp == 0) sOut[w][col] = accO;
  }
  __syncthreads();
  if (tid < 16) {
    float s = bout[0];
#pragma unroll
    for (int q = 0; q < 8; ++q) s += sOut[q][tid];
    out[b0 + tid] = s;
  }
}

extern "C" void kernel_launch(void* const* d_in, const int* in_sizes, int n_in,
                              void* d_out, int out_size, void* d_ws, size_t ws_size,
                              hipStream_t stream) {
  const float* x    = (const float*)d_in[0];
  const float* tme  = (const float*)d_in[1];
  const float* Wc   = (const float*)d_in[2];
  const float* bc   = (const float*)d_in[3];
  const float* Wih1 = (const float*)d_in[4];
  const float* Whh1 = (const float*)d_in[5];
  const float* Wih2 = (const float*)d_in[6];
  const float* Whh2 = (const float*)d_in[7];
  const float* bih2 = (const float*)d_in[8];
  const float* bhh2 = (const float*)d_in[9];
  const float* Wout = (const float*)d_in[10];
  const float* bout = (const float*)d_in[11];
  float* outp = (float*)d_out;
  unsigned* x1u = (unsigned*)d_ws;  // [4096][512] fp16-pair u32 = 8.39 MB

  dim3 gA(16, 32);  // N/64, M/128
  combine_mfma<<<gA, 256, 0, stream>>>(x, tme, Wc, bc, x1u);
  lstm_fused_mfma<<<256, 768, 0, stream>>>(x1u, Wih1, Whh1, Wih2, Whh2,
                                           bih2, bhh2, Wout, bout, outp);
}

// Round 9
// 105.654 us; speedup vs baseline: 1.4162x; 1.1019x over previous
//
#include <hip/hip_runtime.h>
#include <math.h>

// B=4096, S=128, F=8, H1=64, H2=32
// Stage A: x1u = fp16(relu(concat(x,time) @ Wc^T + bc)), fp16 MFMA GEMM
// Stage B: fused LSTM1 || LSTM2(lag-1), 8 waves (2/SIMD), fp16 MFMA,
//          log2e-prescaled weights, persistent C-quads, pkrtz packing.

typedef _Float16 f16x8 __attribute__((ext_vector_type(8)));
typedef float f32x4 __attribute__((ext_vector_type(4)));

union H8 { uint4 q; _Float16 h[8]; f16x8 v; };

#define MF(A, B, C) __builtin_amdgcn_mfma_f32_16x16x32_f16(A, B, C, 0, 0, 0)
#define LOG2E 1.44269504f

// pre-scaled activations: argument y = z * log2(e)
__device__ __forceinline__ float sigm_pre(float y) {
  return __builtin_amdgcn_rcpf(1.f + __builtin_amdgcn_exp2f(-y));
}
__device__ __forceinline__ float tanh_pre(float y) {
  return 1.f - 2.f * __builtin_amdgcn_rcpf(1.f + __builtin_amdgcn_exp2f(y + y));
}
__device__ __forceinline__ float tanh_raw(float c) {
  return 1.f - 2.f * __builtin_amdgcn_rcpf(1.f + __builtin_amdgcn_exp2f(c * 2.88539008f));
}
__device__ __forceinline__ unsigned pkrtz(float a, float b) {
  return __builtin_bit_cast(unsigned, __builtin_amdgcn_cvt_pkrtz(a, b));
}

// ---------------- Kernel A: combine GEMM, fp16 MFMA -------------------------
// M=4096 x N=1024 x K=1024 (+time col + bias + relu), fp16 out. BM=128 BN=64 BK=64.
#define CROW 72  // fp16 slots per staged row (64 + 8 pad) = 144 B

__global__ __launch_bounds__(256, 2) void combine_mfma(
    const float* __restrict__ x, const float* __restrict__ tme,
    const float* __restrict__ Wc, const float* __restrict__ bc,
    unsigned* __restrict__ x1u)   // fp16 pairs: [4096][512] u32
{
  __shared__ __align__(16) _Float16 sA[128][CROW];  // 18432 B
  __shared__ __align__(16) _Float16 sB[64][CROW];   // 9216 B
  __shared__ float sT[128];
  __shared__ float sWl[64];
  __shared__ float sBc[64];
  _Float16 (*Cst)[CROW] = sA;  // epilogue overlay

  const int tid = threadIdx.x;
  const int lane = tid & 63;
  const int w = tid >> 6;
  const int r = lane & 15, grp = lane >> 4;
  const int M0 = blockIdx.y * 128, N0 = blockIdx.x * 64;

  if (tid < 128) sT[tid] = tme[M0 + tid];
  else if (tid < 192) sWl[tid - 128] = Wc[(size_t)(N0 + tid - 128) * 1025 + 1024];
  else sBc[tid - 192] = bc[N0 + tid - 192];

  f32x4 acc[2][4];
#pragma unroll
  for (int i = 0; i < 2; ++i)
#pragma unroll
    for (int j = 0; j < 4; ++j) acc[i][j] = f32x4{0.f, 0.f, 0.f, 0.f};

  for (int kt = 0; kt < 1024; kt += 64) {
    // stage A: 128 rows x 64 k = 2048 float4, 8/thread
#pragma unroll
    for (int i = 0; i < 8; ++i) {
      int idx = tid + i * 256;
      int row = idx >> 4, kq = idx & 15;
      float4 v = *(const float4*)&x[(size_t)(M0 + row) * 1024 + kt + kq * 4];
      *(uint2*)&sA[row][kq * 4] = uint2{pkrtz(v.x, v.y), pkrtz(v.z, v.w)};
    }
    // stage B: 64 rows x 64 k = 1024 float4, 4/thread
#pragma unroll
    for (int i = 0; i < 4; ++i) {
      int idx = tid + i * 256;
      int row = idx >> 4, kq = idx & 15;
      float4 v = *(const float4*)&Wc[(size_t)(N0 + row) * 1025 + kt + kq * 4];
      *(uint2*)&sB[row][kq * 4] = uint2{pkrtz(v.x, v.y), pkrtz(v.z, v.w)};
    }
    __syncthreads();

    H8 af[2][2], bf[4][2];
#pragma unroll
    for (int i = 0; i < 2; ++i)
#pragma unroll
      for (int c = 0; c < 2; ++c)
        af[i][c].q = *(const uint4*)&sA[w * 32 + i * 16 + r][c * 32 + grp * 8];
#pragma unroll
    for (int j = 0; j < 4; ++j)
#pragma unroll
      for (int c = 0; c < 2; ++c)
        bf[j][c].q = *(const uint4*)&sB[j * 16 + r][c * 32 + grp * 8];
#pragma unroll
    for (int i = 0; i < 2; ++i)
#pragma unroll
      for (int j = 0; j < 4; ++j) {
        acc[i][j] = MF(af[i][0].v, bf[j][0].v, acc[i][j]);
        acc[i][j] = MF(af[i][1].v, bf[j][1].v, acc[i][j]);
      }
    __syncthreads();
  }

  // epilogue: time col + bias + relu -> fp16 -> LDS transpose -> coalesced store
#pragma unroll
  for (int i = 0; i < 2; ++i) {
#pragma unroll
    for (int j = 0; j < 4; ++j) {
      int n = j * 16 + r;
      float wl = sWl[n], bv = sBc[n];
#pragma unroll
      for (int q = 0; q < 4; ++q) {
        int mm = w * 32 + i * 16 + 4 * grp + q;
        float v = acc[i][j][q] + sT[mm] * wl + bv;
        Cst[mm][n] = (_Float16)fmaxf(v, 0.f);
      }
    }
  }
  __syncthreads();
#pragma unroll
  for (int i = 0; i < 4; ++i) {   // 128 rows x 8 uint4 = 1024 uint4
    int idx = tid + i * 256;
    int row = idx >> 3, c8 = idx & 7;
    uint4 v = *(const uint4*)&Cst[row][c8 * 8];
    *(uint4*)&x1u[(size_t)(M0 + row) * 512 + (N0 >> 1) + c8 * 4] = v;
  }
}

// ---------------- Kernel B: fused LSTM fp16, 8 waves, lag-1 L2 --------------
// wave w: vw = w>>1, wsub = w&1.
// L1: tiles jj=0,1 -> h1 = vw*16 + 4*grp + 2*wsub + jj.
// L2: tile u = 2*vw + wsub -> h2 = 4*u + grp.
#define ROW1 72   // shorts per sh1 row: 64 h1 slots + 8 pad
#define ROW2 40   // shorts per sh2 row: 32 h2 slots + 8 pad

__global__ __launch_bounds__(512, 2) void lstm_fused_mfma(
    const unsigned* __restrict__ x1u,
    const float* __restrict__ Wih1, const float* __restrict__ Whh1,
    const float* __restrict__ Wih2, const float* __restrict__ Whh2,
    const float* __restrict__ bih2, const float* __restrict__ bhh2,
    const float* __restrict__ Wout, const float* __restrict__ bout,
    float* __restrict__ out)
{
  __shared__ __align__(16) unsigned sxw[128 * 16 * 4];       // fp16 x [t][b][4u32] 32KB
  __shared__ float sWoT[32 * 132];                           // Wout^T [h2][t+pad] 16896B
  __shared__ __align__(16) unsigned short sh1[2][16][ROW1];  // 4608B
  __shared__ __align__(16) unsigned short sh2[2][16][ROW2];  // 2560B
  __shared__ float sOut[8][16];

  const int tid = threadIdx.x;
  const int lane = tid & 63;
  const int w = tid >> 6;       // wave 0..7
  const int vw = w >> 1;
  const int wsub = w & 1;
  const int col = lane & 15;    // A-row at pack time / batch col at run time
  const int grp = lane >> 4;    // k-slot group; C rows 4*grp+r (r = gate)
  const int b0 = blockIdx.x * 16;

  // ---- pack fp16 A-side weight fragments (once), pre-scaled by log2(e) ----
  const int m1 = col >> 2, g1 = col & 3;  // A row = 4*m + gate
  f16x8 A1h[2][2];  // L1 tiles jj: Whh1 chunks c=0,1 (k=64)
  f16x8 A1x[2];     // L1 tiles jj: Wih1 chunk (8 of 32 k-slots)
#pragma unroll
  for (int jj = 0; jj < 2; ++jj) {
    const int wr = g1 * 64 + vw * 16 + 4 * m1 + (2 * wsub + jj);
#pragma unroll
    for (int c = 0; c < 2; ++c) {
      H8 f;
#pragma unroll
      for (int q = 0; q < 8; ++q)
        f.h[q] = (_Float16)(Whh1[wr * 64 + c * 32 + grp * 8 + q] * LOG2E);
      A1h[jj][c] = f.v;
    }
    H8 fx;
#pragma unroll
    for (int q = 0; q < 8; ++q)
      fx.h[q] = (grp == 0) ? (_Float16)(Wih1[wr * 8 + q] * LOG2E) : (_Float16)0.f;
    A1x[jj] = fx.v;
  }
  f16x8 A2[3];  // L2: c0,c1 = Wih2 (k=64), c2 = Whh2 (k=32)
  const int u = 2 * vw + wsub;
  {
    const int wr = g1 * 32 + 4 * u + m1;
#pragma unroll
    for (int c = 0; c < 3; ++c) {
      H8 f;
#pragma unroll
      for (int q = 0; q < 8; ++q) {
        float wv = (c < 2) ? Wih2[wr * 64 + c * 32 + grp * 8 + q]
                           : Whh2[wr * 32 + grp * 8 + q];
        f.h[q] = (_Float16)(wv * LOG2E);
      }
      A2[c] = f.v;
    }
  }
  const int h2o = 4 * u + grp;
  f32x4 b2q;
#pragma unroll
  for (int r = 0; r < 4; ++r)
    b2q[r] = (bih2[r * 32 + h2o] + bhh2[r * 32 + h2o]) * LOG2E;
  const f32x4 zq = {0.f, 0.f, 0.f, 0.f};

  // ---- LDS init ----
  for (int idx = tid; idx < 4096; idx += 512) {  // Wout -> [h2][t], stride 132
    int t = idx >> 5, h = idx & 31;
    sWoT[h * 132 + t] = Wout[idx];
  }
  {
    unsigned short* z = &sh1[0][0][0];
    for (int i2 = tid; i2 < 2 * 16 * ROW1; i2 += 512) z[i2] = 0;
    unsigned short* z2 = &sh2[0][0][0];
    for (int i2 = tid; i2 < 2 * 16 * ROW2; i2 += 512) z2[i2] = 0;
  }
  for (int idx = tid; idx < 16 * 512; idx += 512) {  // x preload: [t][b][4u32]
    int bb = idx >> 9, rem = idx & 511;
    int t = rem >> 2, pr = rem & 3;
    sxw[t * 64 + bb * 4 + pr] = x1u[(size_t)(b0 + bb) * 512 + rem];
  }
  __syncthreads();

  float c1a = 0.f, c1b = 0.f, c2 = 0.f, accO = 0.f;

#define PHASE(T, CUR, DO_L1, DO_L2)                                            \
  {                                                                            \
    H8 s0, s1, s2;                                                             \
    s0.q = *(const uint4*)&sh1[CUR][col][grp * 8];                             \
    s1.q = *(const uint4*)&sh1[CUR][col][32 + grp * 8];                        \
    s2.q = *(const uint4*)&sh2[CUR][col][grp * 8];                             \
    if (DO_L2) {                                                               \
      const float won = sWoT[h2o * 132 + (T) - 1];                             \
      f32x4 a = MF(A2[2], s2.v, b2q);                                          \
      a = MF(A2[0], s0.v, a);                                                  \
      a = MF(A2[1], s1.v, a);                                                  \
      float ig = sigm_pre(a[0]), fg = sigm_pre(a[1]);                          \
      float tg = tanh_pre(a[2]), og = sigm_pre(a[3]);                          \
      float cc = fg * c2 + ig * tg;                                            \
      c2 = cc;                                                                 \
      float hn = og * tanh_raw(cc);                                            \
      accO = fmaf(hn, won, accO);                                              \
      *(_Float16*)&sh2[(CUR) ^ 1][col][h2o] = (_Float16)hn;                    \
    }                                                                          \
    if (DO_L1) {                                                               \
      H8 sx;                                                                   \
      sx.q = *(const uint4*)&sxw[(T) * 64 + col * 4];                          \
      f32x4 a0 = MF(A1x[0], sx.v, zq);                                         \
      f32x4 a1 = MF(A1x[1], sx.v, zq);                                         \
      a0 = MF(A1h[0][0], s0.v, a0);                                            \
      a1 = MF(A1h[1][0], s0.v, a1);                                            \
      a0 = MF(A1h[0][1], s1.v, a0);                                            \
      a1 = MF(A1h[1][1], s1.v, a1);                                            \
      float ig0 = sigm_pre(a0[0]), fg0 = sigm_pre(a0[1]);                      \
      float tg0 = tanh_pre(a0[2]), og0 = sigm_pre(a0[3]);                      \
      float cc0 = fg0 * c1a + ig0 * tg0;                                       \
      c1a = cc0;                                                               \
      float h0 = og0 * tanh_raw(cc0);                                          \
      float ig1 = sigm_pre(a1[0]), fg1 = sigm_pre(a1[1]);                      \
      float tg1 = tanh_pre(a1[2]), og1 = sigm_pre(a1[3]);                      \
      float cc1 = fg1 * c1b + ig1 * tg1;                                       \
      c1b = cc1;                                                               \
      float h1v = og1 * tanh_raw(cc1);                                         \
      *(unsigned*)&sh1[(CUR) ^ 1][col][vw * 16 + 4 * grp + 2 * wsub] =         \
          pkrtz(h0, h1v);                                                      \
    }                                                                          \
    __syncthreads();                                                           \
  }

  PHASE(0, 0, true, false);
  PHASE(1, 1, true, true);
  for (int tt = 1; tt < 64; ++tt) {
    const int t0 = 2 * tt;
    PHASE(t0, 0, true, true);
    PHASE(t0 + 1, 1, true, true);
  }
  PHASE(128, 0, false, true);
#undef PHASE

  // ---- output reduce: over grp (16/32 shuffles) then 8 waves ----
  accO += __shfl_xor(accO, 16);
  accO += __shfl_xor(accO, 32);
  if (grp == 0) sOut[u][col] = accO;
  __syncthreads();
  if (tid < 16) {
    float s = bout[0];
#pragma unroll
    for (int q = 0; q < 8; ++q) s += sOut[q][tid];
    out[b0 + tid] = s;
  }
}

extern "C" void kernel_launch(void* const* d_in, const int* in_sizes, int n_in,
                              void* d_out, int out_size, void* d_ws, size_t ws_size,
                              hipStream_t stream) {
  const float* x    = (const float*)d_in[0];
  const float* tme  = (const float*)d_in[1];
  const float* Wc   = (const float*)d_in[2];
  const float* bc   = (const float*)d_in[3];
  const float* Wih1 = (const float*)d_in[4];
  const float* Whh1 = (const float*)d_in[5];
  const float* Wih2 = (const float*)d_in[6];
  const float* Whh2 = (const float*)d_in[7];
  const float* bih2 = (const float*)d_in[8];
  const float* bhh2 = (const float*)d_in[9];
  const float* Wout = (const float*)d_in[10];
  const float* bout = (const float*)d_in[11];
  float* outp = (float*)d_out;
  unsigned* x1u = (unsigned*)d_ws;  // [4096][512] fp16-pair u32 = 8.39 MB

  dim3 gA(16, 32);  // N/64, M/128
  combine_mfma<<<gA, 256, 0, stream>>>(x, tme, Wc, bc, x1u);
  lstm_fused_mfma<<<256, 512, 0, stream>>>(x1u, Wih1, Whh1, Wih2, Whh2,
                                           bih2, bhh2, Wout, bout, outp);
}